// Round 1
// baseline (981.367 us; speedup 1.0000x reference)
//
#include <hip/hip_runtime.h>
#include <stdint.h>

// Problem constants: N_S=8192, N_H=64, C=64
#define NSQ 8192

// Workspace layout (float offsets). Total ~4.06 MB.
#define WS_X1T  0u                               // X1^T [64][8192]
#define WS_X2T  (64u * 8192u)                    // X2^T [64][8192]
#define WS_RS   (2u * 64u * 8192u)               // rowsum [8192]
#define WS_W2T  (2u * 64u * 8192u + 8192u)       // W2^T [64][64] (W2T[h*64+i] = W2[i*64+h])
#define WS_FLAG (2u * 64u * 8192u + 8192u + 4096u) // 1 uint: mask-dtype flag

// ---------------------------------------------------------------------------
// init: zero rowsum + flag, build W2T
__global__ __launch_bounds__(256) void k_init(const float* __restrict__ W2,
                                              float* __restrict__ ws) {
    int t = threadIdx.x, b = blockIdx.x;
    ws[WS_RS + b * 256 + t] = 0.0f;   // 32 blocks x 256 = 8192
    if (b == 0) {
#pragma unroll
        for (int q = 0; q < 16; ++q) {
            int e = q * 256 + t;
            int i = e >> 6, h = e & 63;
            ws[WS_W2T + h * 64 + i] = W2[i * 64 + h];
        }
        if (t == 0) ((unsigned*)ws)[WS_FLAG] = 0u;
    }
}

// ---------------------------------------------------------------------------
// detect mask dtype: reads first 64 MB (valid for u8 / i32 / f32 layouts).
// f32 mask -> words == 0x3f800000 ; u8 packed -> words > 1 ; i32 -> words in {0,1}
__global__ __launch_bounds__(256) void k_detect(const uint4* __restrict__ m,
                                                unsigned* __restrict__ flag) {
    __shared__ unsigned bf;
    int t = threadIdx.x;
    if (t == 0) bf = 0u;
    __syncthreads();
    size_t idx = (size_t)blockIdx.x * 256 + t;
    uint4 v = m[idx];
    unsigned a[4] = {v.x, v.y, v.z, v.w};
    unsigned lf = 0u;
#pragma unroll
    for (int q = 0; q < 4; ++q) {
        if (a[q] == 0x3f800000u) lf |= 2u;
        else if (a[q] > 1u)      lf |= 1u;
    }
    if (lf) atomicOr(&bf, lf);
    __syncthreads();
    if (t == 0 && bf) atomicOr(flag, bf);
}

// ---------------------------------------------------------------------------
// prep A: Y[s,h] = sum_c H'[s,c,h]*w1[c];  X1[s,i] = sum_h Y[s,h]*W2[i,h]
// stores transposed: X1T[i*8192+s]
__global__ __launch_bounds__(256) void k_prep_a(const float* __restrict__ H,
                                                const float* __restrict__ w1,
                                                const float* __restrict__ w2t,
                                                float* __restrict__ X1T) {
    __shared__ float ylds[4][64];
    int t = threadIdx.x;
    int sl = t >> 6, h = t & 63;
    size_t s = (size_t)blockIdx.x * 4 + sl;
    const float* hp = H + s * 4096;
    float acc = 0.f;
#pragma unroll
    for (int c = 0; c < 64; ++c) acc = fmaf(hp[c * 64 + h], w1[c], acc);
    ylds[sl][h] = acc;
    __syncthreads();
    float a1 = 0.f;
#pragma unroll
    for (int hh = 0; hh < 64; ++hh) a1 = fmaf(ylds[sl][hh], w2t[hh * 64 + h], a1);
    X1T[(size_t)h * NSQ + s] = a1;   // here lane index h plays role of output index i
}

// ---------------------------------------------------------------------------
// prep X2: X2[s,c] = sum_h H'[s,c,h]*w3[h]; stores X2T[c*8192+s]
__global__ __launch_bounds__(256) void k_prep_x2(const float* __restrict__ H,
                                                 const float* __restrict__ w3,
                                                 float* __restrict__ X2T) {
    int t = threadIdx.x;
    int sl = t >> 6, c = t & 63;
    size_t s = (size_t)blockIdx.x * 4 + sl;
    const float4* hp = (const float4*)(H + s * 4096 + c * 64);
    const float4* w4 = (const float4*)w3;
    float acc = 0.f;
#pragma unroll
    for (int q = 0; q < 16; ++q) {
        float4 hv = hp[q], wv = w4[q];
        acc += hv.x * wv.x + hv.y * wv.y + hv.z * wv.z + hv.w * wv.w;
    }
    X2T[(size_t)c * NSQ + s] = acc;
}

// ---------------------------------------------------------------------------
// main: per 128x128 tile, S = X1 X2^T (fp32 register-tiled), then
// ee = exp(V*sigmoid(S+B))*mask -> d_out, row-sum partials -> atomicAdd
__global__ __launch_bounds__(256) void k_main(const float* __restrict__ X1T,
                                              const float* __restrict__ X2T,
                                              const float* __restrict__ V,
                                              const float* __restrict__ Bm,
                                              const void* __restrict__ mask,
                                              const unsigned* __restrict__ flag,
                                              float* __restrict__ out,
                                              float* __restrict__ rowsum) {
    __shared__ float as_[64 * 128];
    __shared__ float bs_[64 * 128];
    int t = threadIdx.x;
    int tx = t & 15, ty = t >> 4;
    int rowBase = blockIdx.y * 128;
    int colBase = blockIdx.x * 128;

    // stage: both tiles are [k][m] rows of 128 contiguous floats in global (transposed inputs)
#pragma unroll
    for (int it = 0; it < 8; ++it) {
        int f4 = it * 256 + t;        // 0..2047
        int k  = f4 >> 5;             // 0..63
        int mq = (f4 & 31) * 4;       // 0..124
        float4 av = *(const float4*)(X1T + (size_t)k * NSQ + rowBase + mq);
        float4 bv = *(const float4*)(X2T + (size_t)k * NSQ + colBase + mq);
        *(float4*)&as_[k * 128 + mq] = av;
        *(float4*)&bs_[k * 128 + mq] = bv;
    }
    __syncthreads();

    float acc[8][8];
#pragma unroll
    for (int i = 0; i < 8; ++i)
#pragma unroll
        for (int j = 0; j < 8; ++j) acc[i][j] = 0.f;

    // rows: rowBase + ty*8 + i (broadcast reads, conflict-free)
    // cols: colBase + tx*4 + j (j<4), colBase + 64 + tx*4 + (j-4) (j>=4)  -> 2-way LDS (free)
#pragma unroll 4
    for (int k = 0; k < 64; ++k) {
        float4 a0 = *(const float4*)&as_[k * 128 + ty * 8];
        float4 a1 = *(const float4*)&as_[k * 128 + ty * 8 + 4];
        float4 b0 = *(const float4*)&bs_[k * 128 + tx * 4];
        float4 b1 = *(const float4*)&bs_[k * 128 + 64 + tx * 4];
        float am[8] = {a0.x, a0.y, a0.z, a0.w, a1.x, a1.y, a1.z, a1.w};
        float bn[8] = {b0.x, b0.y, b0.z, b0.w, b1.x, b1.y, b1.z, b1.w};
#pragma unroll
        for (int i = 0; i < 8; ++i)
#pragma unroll
            for (int j = 0; j < 8; ++j) acc[i][j] = fmaf(am[i], bn[j], acc[i][j]);
    }

    unsigned fl = *flag;
#pragma unroll
    for (int i = 0; i < 8; ++i) {
        int row = rowBase + ty * 8 + i;
        size_t base1 = (size_t)row * NSQ + colBase + tx * 4;
        size_t base2 = base1 + 64;
        float4 v0 = *(const float4*)(V + base1);
        float4 v1 = *(const float4*)(V + base2);
        float4 c0 = *(const float4*)(Bm + base1);
        float4 c1 = *(const float4*)(Bm + base2);
        float mv[8];
        if (fl & 2u) {           // float32 mask
            float4 m0 = *(const float4*)((const float*)mask + base1);
            float4 m1 = *(const float4*)((const float*)mask + base2);
            mv[0] = (m0.x != 0.f) ? 1.f : 0.f; mv[1] = (m0.y != 0.f) ? 1.f : 0.f;
            mv[2] = (m0.z != 0.f) ? 1.f : 0.f; mv[3] = (m0.w != 0.f) ? 1.f : 0.f;
            mv[4] = (m1.x != 0.f) ? 1.f : 0.f; mv[5] = (m1.y != 0.f) ? 1.f : 0.f;
            mv[6] = (m1.z != 0.f) ? 1.f : 0.f; mv[7] = (m1.w != 0.f) ? 1.f : 0.f;
        } else if (fl & 1u) {    // uint8 (packed bool) mask
            unsigned u0 = *(const unsigned*)((const uint8_t*)mask + base1);
            unsigned u1 = *(const unsigned*)((const uint8_t*)mask + base2);
            mv[0] = (u0 & 0x000000ffu) ? 1.f : 0.f; mv[1] = (u0 & 0x0000ff00u) ? 1.f : 0.f;
            mv[2] = (u0 & 0x00ff0000u) ? 1.f : 0.f; mv[3] = (u0 & 0xff000000u) ? 1.f : 0.f;
            mv[4] = (u1 & 0x000000ffu) ? 1.f : 0.f; mv[5] = (u1 & 0x0000ff00u) ? 1.f : 0.f;
            mv[6] = (u1 & 0x00ff0000u) ? 1.f : 0.f; mv[7] = (u1 & 0xff000000u) ? 1.f : 0.f;
        } else {                 // int32 mask
            int4 i0 = *(const int4*)((const int*)mask + base1);
            int4 i1 = *(const int4*)((const int*)mask + base2);
            mv[0] = i0.x ? 1.f : 0.f; mv[1] = i0.y ? 1.f : 0.f;
            mv[2] = i0.z ? 1.f : 0.f; mv[3] = i0.w ? 1.f : 0.f;
            mv[4] = i1.x ? 1.f : 0.f; mv[5] = i1.y ? 1.f : 0.f;
            mv[6] = i1.z ? 1.f : 0.f; mv[7] = i1.w ? 1.f : 0.f;
        }
        float vv[8] = {v0.x, v0.y, v0.z, v0.w, v1.x, v1.y, v1.z, v1.w};
        float bb[8] = {c0.x, c0.y, c0.z, c0.w, c1.x, c1.y, c1.z, c1.w};
        float e[8];
        float rs = 0.f;
#pragma unroll
        for (int j = 0; j < 8; ++j) {
            float x  = acc[i][j] + bb[j];
            float sg = 1.0f / (1.0f + __expf(-x));
            float ev = vv[j] * sg;
            float r  = mv[j] * __expf(ev);
            e[j] = r; rs += r;
        }
        *(float4*)(out + base1) = make_float4(e[0], e[1], e[2], e[3]);
        *(float4*)(out + base2) = make_float4(e[4], e[5], e[6], e[7]);
        rs += __shfl_xor(rs, 1);
        rs += __shfl_xor(rs, 2);
        rs += __shfl_xor(rs, 4);
        rs += __shfl_xor(rs, 8);
        if (tx == 0) atomicAdd(&rowsum[row], rs);
    }
}

// ---------------------------------------------------------------------------
// normalize: A = ee / (rowsum + 1e-6)
__global__ __launch_bounds__(256) void k_norm(float* __restrict__ out,
                                              const float* __restrict__ rowsum) {
    size_t idx = (size_t)blockIdx.x * 256 + threadIdx.x;   // float4 index
    int row = (int)(idx >> 11);                            // 2048 float4 per row
    float inv = 1.0f / (rowsum[row] + 1e-6f);
    float4* p = (float4*)out;
    float4 v = p[idx];
    v.x *= inv; v.y *= inv; v.z *= inv; v.w *= inv;
    p[idx] = v;
}

// ---------------------------------------------------------------------------
extern "C" void kernel_launch(void* const* d_in, const int* in_sizes, int n_in,
                              void* d_out, int out_size, void* d_ws, size_t ws_size,
                              hipStream_t stream) {
    const float* H    = (const float*)d_in[0];  // [8192,64,64]
    const float* w1   = (const float*)d_in[1];  // [64]
    const float* W2   = (const float*)d_in[2];  // [64,64]
    const float* w3   = (const float*)d_in[3];  // [64]
    const float* V    = (const float*)d_in[4];  // [8192,8192]
    const float* Bm   = (const float*)d_in[5];  // [8192,8192]
    const void*  mask = d_in[6];                // [8192,8192] dtype detected at runtime
    float* out = (float*)d_out;
    float* ws  = (float*)d_ws;

    float*    X1T    = ws + WS_X1T;
    float*    X2T    = ws + WS_X2T;
    float*    rowsum = ws + WS_RS;
    float*    w2t    = ws + WS_W2T;
    unsigned* flag   = (unsigned*)(ws + WS_FLAG);

    k_init   <<<32,            256, 0, stream>>>(W2, ws);
    k_detect <<<16384,         256, 0, stream>>>((const uint4*)mask, flag);
    k_prep_a <<<2048,          256, 0, stream>>>(H, w1, w2t, X1T);
    k_prep_x2<<<2048,          256, 0, stream>>>(H, w3, X2T);
    k_main   <<<dim3(64, 64),  256, 0, stream>>>(X1T, X2T, V, Bm, mask, flag, out, rowsum);
    k_norm   <<<65536,         256, 0, stream>>>(out, rowsum);
}

// Round 2
// 940.943 us; speedup vs baseline: 1.0430x; 1.0430x over previous
//
#include <hip/hip_runtime.h>
#include <stdint.h>

// Problem constants: N_S=8192, N_H=64, C=64
#define NSQ 8192

// Workspace layout (float offsets). Total ~4.06 MB.
#define WS_X1T  0u                                 // X1^T [64][8192]
#define WS_X2T  (64u * 8192u)                      // X2^T [64][8192]
#define WS_RS   (2u * 64u * 8192u)                 // rowsum [8192]
#define WS_W2T  (2u * 64u * 8192u + 8192u)         // W2^T [64][64]
#define WS_FLAG (2u * 64u * 8192u + 8192u + 4096u) // 1 uint: mask-dtype flag

// ---------------------------------------------------------------------------
// init: zero rowsum + flag, build W2T (W2T[h*64+i] = W2[i*64+h])
__global__ __launch_bounds__(256) void k_init(const float* __restrict__ W2,
                                              float* __restrict__ ws) {
    int t = threadIdx.x, b = blockIdx.x;
    ws[WS_RS + b * 256 + t] = 0.0f;   // 32 blocks x 256 = 8192
    if (b == 0) {
#pragma unroll
        for (int q = 0; q < 16; ++q) {
            int e = q * 256 + t;
            int i = e >> 6, h = e & 63;
            ws[WS_W2T + h * 64 + i] = W2[i * 64 + h];
        }
        if (t == 0) ((unsigned*)ws)[WS_FLAG] = 0u;
    }
}

// ---------------------------------------------------------------------------
// detect mask dtype from a 4 MB sample (1% density -> thousands of nonzeros
// in any candidate layout; false-negative probability ~0).
// f32 mask -> words == 0x3f800000 ; u8 packed -> some word > 1 ; i32 -> {0,1}
__global__ __launch_bounds__(256) void k_detect(const uint4* __restrict__ m,
                                                unsigned* __restrict__ flag) {
    __shared__ unsigned bf;
    int t = threadIdx.x;
    if (t == 0) bf = 0u;
    __syncthreads();
    size_t idx = (size_t)blockIdx.x * 256 + t;
    uint4 v = m[idx];
    unsigned a[4] = {v.x, v.y, v.z, v.w};
    unsigned lf = 0u;
#pragma unroll
    for (int q = 0; q < 4; ++q) {
        if (a[q] == 0x3f800000u) lf |= 2u;
        else if (a[q] > 1u)      lf |= 1u;
    }
    if (lf) atomicOr(&bf, lf);
    __syncthreads();
    if (t == 0 && bf) atomicOr(flag, bf);
}

// ---------------------------------------------------------------------------
// fused prep: reads H' ONCE (float4), computes
//   Y[s,h]  = sum_c H'[s,c,h]*w1[c]          (wave shuffle-reduce over c-groups)
//   X1[s,i] = sum_h Y[s,h]*W2[i,h]           -> X1T[i*8192+s]
//   X2[s,c] = sum_h H'[s,c,h]*w3[h]          -> X2T[c*8192+s]
// 4 s per block (one per wave); lane l: cq=l>>4 owns c-range, hq=l&15 owns h4.
__global__ __launch_bounds__(256) void k_prep(const float* __restrict__ H,
                                              const float* __restrict__ w1,
                                              const float* __restrict__ w3,
                                              const float* __restrict__ w2t,
                                              float* __restrict__ X1T,
                                              float* __restrict__ X2T) {
    __shared__ float ylds[4][64];
    int t = threadIdx.x;
    int sl = t >> 6, l = t & 63;
    int cq = l >> 4, hq = l & 15;
    size_t s = (size_t)blockIdx.x * 4 + sl;
    const float* hp = H + s * 4096;
    float4 w3q = *(const float4*)(w3 + hq * 4);
    float4 yacc = make_float4(0.f, 0.f, 0.f, 0.f);
    float x2p[16];
#pragma unroll
    for (int cc = 0; cc < 16; ++cc) {
        int c = cq * 16 + cc;
        float4 hv = *(const float4*)(hp + c * 64 + hq * 4);
        float wc = w1[c];
        yacc.x = fmaf(hv.x, wc, yacc.x);
        yacc.y = fmaf(hv.y, wc, yacc.y);
        yacc.z = fmaf(hv.z, wc, yacc.z);
        yacc.w = fmaf(hv.w, wc, yacc.w);
        x2p[cc] = hv.x * w3q.x + hv.y * w3q.y + hv.z * w3q.z + hv.w * w3q.w;
    }
    // X2: reduce partials over the 16 hq lanes of each cq group (lane bits 0..3)
#pragma unroll
    for (int cc = 0; cc < 16; ++cc) {
        float v = x2p[cc];
        v += __shfl_xor(v, 1);
        v += __shfl_xor(v, 2);
        v += __shfl_xor(v, 4);
        v += __shfl_xor(v, 8);
        x2p[cc] = v;
    }
    if (hq == 0) {
#pragma unroll
        for (int cc = 0; cc < 16; ++cc)
            X2T[(size_t)(cq * 16 + cc) * NSQ + s] = x2p[cc];
    }
    // Y: reduce partials over the 4 cq groups (lane bits 4..5)
    yacc.x += __shfl_xor(yacc.x, 16); yacc.x += __shfl_xor(yacc.x, 32);
    yacc.y += __shfl_xor(yacc.y, 16); yacc.y += __shfl_xor(yacc.y, 32);
    yacc.z += __shfl_xor(yacc.z, 16); yacc.z += __shfl_xor(yacc.z, 32);
    yacc.w += __shfl_xor(yacc.w, 16); yacc.w += __shfl_xor(yacc.w, 32);
    if (cq == 0) *(float4*)&ylds[sl][hq * 4] = yacc;
    __syncthreads();
    float a1 = 0.f;
    int i = l;
#pragma unroll
    for (int h = 0; h < 64; ++h) a1 = fmaf(ylds[sl][h], w2t[h * 64 + i], a1);
    X1T[(size_t)i * NSQ + s] = a1;
}

// ---------------------------------------------------------------------------
// main: per 128x128 tile, S = X1 X2^T (fp32 register-tiled, K split in two
// 32-deep phases so LDS = 32 KB -> 5 blocks/CU), then
// ee = exp(V*sigmoid(S+B))*mask -> d_out, row-sum partials -> atomicAdd
__global__ __launch_bounds__(256, 4) void k_main(const float* __restrict__ X1T,
                                                 const float* __restrict__ X2T,
                                                 const float* __restrict__ V,
                                                 const float* __restrict__ Bm,
                                                 const void* __restrict__ mask,
                                                 const unsigned* __restrict__ flag,
                                                 float* __restrict__ out,
                                                 float* __restrict__ rowsum) {
    __shared__ float as_[32 * 128];
    __shared__ float bs_[32 * 128];
    int t = threadIdx.x;
    int tx = t & 15, ty = t >> 4;
    int rowBase = blockIdx.y * 128;
    int colBase = blockIdx.x * 128;

    float acc[8][8];
#pragma unroll
    for (int i = 0; i < 8; ++i)
#pragma unroll
        for (int j = 0; j < 8; ++j) acc[i][j] = 0.f;

#pragma unroll
    for (int phase = 0; phase < 2; ++phase) {
        int kbase = phase * 32;
        if (phase) __syncthreads();   // protect LDS reuse
#pragma unroll
        for (int it = 0; it < 4; ++it) {
            int f4 = it * 256 + t;        // 0..1023
            int k  = f4 >> 5;             // 0..31
            int mq = (f4 & 31) * 4;       // 0..124
            float4 av = *(const float4*)(X1T + (size_t)(kbase + k) * NSQ + rowBase + mq);
            float4 bv = *(const float4*)(X2T + (size_t)(kbase + k) * NSQ + colBase + mq);
            *(float4*)&as_[k * 128 + mq] = av;
            *(float4*)&bs_[k * 128 + mq] = bv;
        }
        __syncthreads();

        // rows: ty*8+i (broadcast, conflict-free); cols: tx*4+j / 64+tx*4+j (2-way, free)
#pragma unroll 4
        for (int k = 0; k < 32; ++k) {
            float4 a0 = *(const float4*)&as_[k * 128 + ty * 8];
            float4 a1 = *(const float4*)&as_[k * 128 + ty * 8 + 4];
            float4 b0 = *(const float4*)&bs_[k * 128 + tx * 4];
            float4 b1 = *(const float4*)&bs_[k * 128 + 64 + tx * 4];
            float am[8] = {a0.x, a0.y, a0.z, a0.w, a1.x, a1.y, a1.z, a1.w};
            float bn[8] = {b0.x, b0.y, b0.z, b0.w, b1.x, b1.y, b1.z, b1.w};
#pragma unroll
            for (int i = 0; i < 8; ++i)
#pragma unroll
                for (int j = 0; j < 8; ++j) acc[i][j] = fmaf(am[i], bn[j], acc[i][j]);
        }
    }

    unsigned fl = *flag;
#pragma unroll
    for (int i = 0; i < 8; ++i) {
        int row = rowBase + ty * 8 + i;
        size_t base1 = (size_t)row * NSQ + colBase + tx * 4;
        size_t base2 = base1 + 64;
        float4 v0 = *(const float4*)(V + base1);
        float4 v1 = *(const float4*)(V + base2);
        float4 c0 = *(const float4*)(Bm + base1);
        float4 c1 = *(const float4*)(Bm + base2);
        float mv[8];
        if (fl & 2u) {           // float32 mask
            float4 m0 = *(const float4*)((const float*)mask + base1);
            float4 m1 = *(const float4*)((const float*)mask + base2);
            mv[0] = (m0.x != 0.f) ? 1.f : 0.f; mv[1] = (m0.y != 0.f) ? 1.f : 0.f;
            mv[2] = (m0.z != 0.f) ? 1.f : 0.f; mv[3] = (m0.w != 0.f) ? 1.f : 0.f;
            mv[4] = (m1.x != 0.f) ? 1.f : 0.f; mv[5] = (m1.y != 0.f) ? 1.f : 0.f;
            mv[6] = (m1.z != 0.f) ? 1.f : 0.f; mv[7] = (m1.w != 0.f) ? 1.f : 0.f;
        } else if (fl & 1u) {    // uint8 (packed bool) mask
            unsigned u0 = *(const unsigned*)((const uint8_t*)mask + base1);
            unsigned u1 = *(const unsigned*)((const uint8_t*)mask + base2);
            mv[0] = (u0 & 0x000000ffu) ? 1.f : 0.f; mv[1] = (u0 & 0x0000ff00u) ? 1.f : 0.f;
            mv[2] = (u0 & 0x00ff0000u) ? 1.f : 0.f; mv[3] = (u0 & 0xff000000u) ? 1.f : 0.f;
            mv[4] = (u1 & 0x000000ffu) ? 1.f : 0.f; mv[5] = (u1 & 0x0000ff00u) ? 1.f : 0.f;
            mv[6] = (u1 & 0x00ff0000u) ? 1.f : 0.f; mv[7] = (u1 & 0xff000000u) ? 1.f : 0.f;
        } else {                 // int32 mask
            int4 i0 = *(const int4*)((const int*)mask + base1);
            int4 i1 = *(const int4*)((const int*)mask + base2);
            mv[0] = i0.x ? 1.f : 0.f; mv[1] = i0.y ? 1.f : 0.f;
            mv[2] = i0.z ? 1.f : 0.f; mv[3] = i0.w ? 1.f : 0.f;
            mv[4] = i1.x ? 1.f : 0.f; mv[5] = i1.y ? 1.f : 0.f;
            mv[6] = i1.z ? 1.f : 0.f; mv[7] = i1.w ? 1.f : 0.f;
        }
        float vv[8] = {v0.x, v0.y, v0.z, v0.w, v1.x, v1.y, v1.z, v1.w};
        float bb[8] = {c0.x, c0.y, c0.z, c0.w, c1.x, c1.y, c1.z, c1.w};
        float e[8];
        float rs = 0.f;
#pragma unroll
        for (int j = 0; j < 8; ++j) {
            float x  = acc[i][j] + bb[j];
            float sg = 1.0f / (1.0f + __expf(-x));
            float ev = vv[j] * sg;
            float r  = mv[j] * __expf(ev);
            e[j] = r; rs += r;
        }
        *(float4*)(out + base1) = make_float4(e[0], e[1], e[2], e[3]);
        *(float4*)(out + base2) = make_float4(e[4], e[5], e[6], e[7]);
        rs += __shfl_xor(rs, 1);
        rs += __shfl_xor(rs, 2);
        rs += __shfl_xor(rs, 4);
        rs += __shfl_xor(rs, 8);
        if (tx == 0) atomicAdd(&rowsum[row], rs);
    }
}

// ---------------------------------------------------------------------------
// normalize: A = ee / (rowsum + 1e-6). One row per block; 8 independent
// float4 loads per thread so latency is hidden (was 1 load/thread -> latency-bound).
__global__ __launch_bounds__(256) void k_norm(float* __restrict__ out,
                                              const float* __restrict__ rowsum) {
    int row = blockIdx.x;
    int t = threadIdx.x;
    float inv = 1.0f / (rowsum[row] + 1e-6f);
    float4* p = (float4*)out + (size_t)row * 2048;
    float4 v[8];
#pragma unroll
    for (int q = 0; q < 8; ++q) v[q] = p[t + q * 256];
#pragma unroll
    for (int q = 0; q < 8; ++q) {
        v[q].x *= inv; v[q].y *= inv; v[q].z *= inv; v[q].w *= inv;
        p[t + q * 256] = v[q];
    }
}

// ---------------------------------------------------------------------------
extern "C" void kernel_launch(void* const* d_in, const int* in_sizes, int n_in,
                              void* d_out, int out_size, void* d_ws, size_t ws_size,
                              hipStream_t stream) {
    const float* H    = (const float*)d_in[0];  // [8192,64,64]
    const float* w1   = (const float*)d_in[1];  // [64]
    const float* W2   = (const float*)d_in[2];  // [64,64]
    const float* w3   = (const float*)d_in[3];  // [64]
    const float* V    = (const float*)d_in[4];  // [8192,8192]
    const float* Bm   = (const float*)d_in[5];  // [8192,8192]
    const void*  mask = d_in[6];                // [8192,8192] dtype detected at runtime
    float* out = (float*)d_out;
    float* ws  = (float*)d_ws;

    float*    X1T    = ws + WS_X1T;
    float*    X2T    = ws + WS_X2T;
    float*    rowsum = ws + WS_RS;
    float*    w2t    = ws + WS_W2T;
    unsigned* flag   = (unsigned*)(ws + WS_FLAG);

    k_init   <<<32,           256, 0, stream>>>(W2, ws);
    k_detect <<<1024,         256, 0, stream>>>((const uint4*)mask, flag);
    k_prep   <<<2048,         256, 0, stream>>>(H, w1, w3, w2t, X1T, X2T);
    k_main   <<<dim3(64, 64), 256, 0, stream>>>(X1T, X2T, V, Bm, mask, flag, out, rowsum);
    k_norm   <<<8192,         256, 0, stream>>>(out, rowsum);
}